// Round 1
// baseline (3450.922 us; speedup 1.0000x reference)
//
#include <hip/hip_runtime.h>
#include <hip/hip_bf16.h>

#define HW256 65536      // 256*256
#define HW1K  1048576    // 1024*1024

// ---------------------------------------------------------------------------
// 4x bilinear downsample 1024->256. scale=4 => ys=4i+1.5 -> exact 2x2 average
// of rows 4i+1,4i+2 / cols 4j+1,4j+2.
__global__ void downsample4(const float* __restrict__ x, float* __restrict__ out) {
    int idx = blockIdx.x * blockDim.x + threadIdx.x;
    if (idx >= 2 * 3 * HW256) return;
    int xo = idx & 255;
    int yo = (idx >> 8) & 255;
    int c  = idx >> 16;                // b*3+ch, 0..5
    const float* p = x + (size_t)c * HW1K;
    int yi = 4 * yo + 1, xi = 4 * xo + 1;
    float s = p[yi * 1024 + xi] + p[yi * 1024 + xi + 1]
            + p[(yi + 1) * 1024 + xi] + p[(yi + 1) * 1024 + xi + 1];
    out[idx] = 0.25f * s;
}

// ---------------------------------------------------------------------------
// Direct 3x3 SAME conv, NCHW, 256x256 spatial. One thread per output pixel of
// one output channel. Weights for this block's co staged in LDS.
template <int CIN>
__global__ void conv3x3(const float* __restrict__ in, const float* __restrict__ wgt,
                        const float* __restrict__ bias, float* __restrict__ out,
                        int cout, int do_relu) {
    const int x  = threadIdx.x;        // 0..255 (one row per block)
    const int y  = blockIdx.x;         // 0..255
    const int co = blockIdx.y;
    const int b  = blockIdx.z;

    __shared__ float ws_[CIN * 9];
    for (int i = threadIdx.x; i < CIN * 9; i += blockDim.x)
        ws_[i] = wgt[co * CIN * 9 + i];
    __syncthreads();

    const float* inb = in + (size_t)b * CIN * HW256;
    float acc = bias[co];
    for (int ci = 0; ci < CIN; ++ci) {
        const float* inc = inb + (size_t)ci * HW256;
        #pragma unroll
        for (int ky = 0; ky < 3; ++ky) {
            int yy = y + ky - 1;
            if (yy < 0 || yy > 255) continue;
            const float* row = inc + yy * 256;
            float v0 = (x >= 1)   ? row[x - 1] : 0.0f;
            float v1 = row[x];
            float v2 = (x <= 254) ? row[x + 1] : 0.0f;
            const float* wk = ws_ + ci * 9 + ky * 3;
            acc += wk[0] * v0 + wk[1] * v1 + wk[2] * v2;
        }
    }
    if (do_relu) acc = fmaxf(acc, 0.0f);
    out[(size_t)(b * cout + co) * HW256 + y * 256 + x] = acc;
}

// ---------------------------------------------------------------------------
// 16x bilinear downsample 256->16 (96 ch). ys=16i+7.5 -> exact 2x2 average of
// rows 16i+7,16i+8.
__global__ void pool16(const float* __restrict__ in, float* __restrict__ out) {
    int idx = blockIdx.x * blockDim.x + threadIdx.x;
    if (idx >= 2 * 96 * 256) return;
    int gx = idx & 15;
    int gy = (idx >> 4) & 15;
    int c  = idx >> 8;                 // b*96+ch, 0..191
    const float* p = in + (size_t)c * HW256;
    int yi = 16 * gy + 7, xi = 16 * gx + 7;
    float s = p[yi * 256 + xi] + p[yi * 256 + xi + 1]
            + p[(yi + 1) * 256 + xi] + p[(yi + 1) * 256 + xi + 1];
    out[idx] = 0.25f * s;
}

// ---------------------------------------------------------------------------
// Fused guide + trilinear grid slice + affine color transform + clip.
// c16 layout: (B, 96, 16, 16); grid[b,p,gy,gx,d] == c16[b, p*8+d, gy, gx].
__global__ void slice_apply(const float* __restrict__ x, const float* __restrict__ c16,
                            float* __restrict__ out) {
    int idx = blockIdx.x * blockDim.x + threadIdx.x;
    if (idx >= 2 * HW1K) return;
    int px = idx & 1023;
    int py = (idx >> 10) & 1023;
    int b  = idx >> 20;

    const float* xb = x + (size_t)b * 3 * HW1K;
    int po = py * 1024 + px;
    float r  = xb[po];
    float g  = xb[HW1K + po];
    float bl = xb[2 * HW1K + po];

    float gd = fminf(fmaxf(0.299f * r + 0.587f * g + 0.114f * bl, 0.0f), 1.0f);

    float ysf = (float)py * (15.0f / 1023.0f);
    float xsf = (float)px * (15.0f / 1023.0f);
    int y0 = (int)floorf(ysf); int y1 = min(y0 + 1, 15);
    int x0 = (int)floorf(xsf); int x1 = min(x0 + 1, 15);
    float wy = ysf - (float)y0;
    float wx = xsf - (float)x0;

    float d  = gd * 7.0f;
    int d0 = (int)floorf(d); d0 = max(0, min(d0, 7));
    int d1 = min(d0 + 1, 7);
    float wd = fminf(fmaxf(d - (float)d0, 0.0f), 1.0f);

    float w00 = (1.0f - wy) * (1.0f - wx);
    float w01 = (1.0f - wy) * wx;
    float w10 = wy * (1.0f - wx);
    float w11 = wy * wx;

    const float* gb = c16 + (size_t)b * 96 * 256;
    float co[12];
    #pragma unroll
    for (int p = 0; p < 12; ++p) {
        const float* gp = gb + p * 8 * 256;   // channel = p*8 + d, stride 256 per ch
        float v00 = (1.0f - wd) * gp[d0 * 256 + y0 * 16 + x0] + wd * gp[d1 * 256 + y0 * 16 + x0];
        float v01 = (1.0f - wd) * gp[d0 * 256 + y0 * 16 + x1] + wd * gp[d1 * 256 + y0 * 16 + x1];
        float v10 = (1.0f - wd) * gp[d0 * 256 + y1 * 16 + x0] + wd * gp[d1 * 256 + y1 * 16 + x0];
        float v11 = (1.0f - wd) * gp[d0 * 256 + y1 * 16 + x1] + wd * gp[d1 * 256 + y1 * 16 + x1];
        co[p] = w00 * v00 + w01 * v01 + w10 * v10 + w11 * v11;
    }

    float* ob = out + (size_t)b * 3 * HW1K;
    #pragma unroll
    for (int i = 0; i < 3; ++i) {
        float v = co[i * 4 + 0] * r + co[i * 4 + 1] * g + co[i * 4 + 2] * bl + co[i * 4 + 3];
        ob[i * HW1K + po] = fminf(fmaxf(v, 0.0f), 1.0f);
    }
}

// ---------------------------------------------------------------------------
extern "C" void kernel_launch(void* const* d_in, const int* in_sizes, int n_in,
                              void* d_out, int out_size, void* d_ws, size_t ws_size,
                              hipStream_t stream) {
    const float* x  = (const float*)d_in[0];
    const float* w1 = (const float*)d_in[1];  const float* b1 = (const float*)d_in[2];
    const float* w2 = (const float*)d_in[3];  const float* b2 = (const float*)d_in[4];
    const float* w3 = (const float*)d_in[5];  const float* b3 = (const float*)d_in[6];
    const float* w4 = (const float*)d_in[7];  const float* b4 = (const float*)d_in[8];
    const float* w5 = (const float*)d_in[9];  const float* b5 = (const float*)d_in[10];
    const float* w6 = (const float*)d_in[11]; const float* b6 = (const float*)d_in[12];
    float* out = (float*)d_out;

    // Workspace layout (floats):
    //   bufA: 2*64*65536  = 8388608   (holds f1(16), f3(32), f5(64))
    //   bufB: 2*96*65536  = 12582912  (holds f2(32), f4(64), f6(96))
    //   xlow: 2*3*65536   = 393216
    //   c16 : 2*96*256    = 49152
    float* bufA = (float*)d_ws;
    float* bufB = bufA + 8388608;
    float* xlow = bufB + 12582912;
    float* c16  = xlow + 393216;

    // 1) downsample x -> xlow (256x256)
    downsample4<<<dim3((2 * 3 * HW256 + 255) / 256), dim3(256), 0, stream>>>(x, xlow);

    // 2) conv stack
    conv3x3<3> <<<dim3(256, 16, 2), dim3(256), 0, stream>>>(xlow, w1, b1, bufA, 16, 1);
    conv3x3<16><<<dim3(256, 32, 2), dim3(256), 0, stream>>>(bufA, w2, b2, bufB, 32, 1);
    conv3x3<32><<<dim3(256, 32, 2), dim3(256), 0, stream>>>(bufB, w3, b3, bufA, 32, 1);
    conv3x3<32><<<dim3(256, 64, 2), dim3(256), 0, stream>>>(bufA, w4, b4, bufB, 64, 1);
    conv3x3<64><<<dim3(256, 64, 2), dim3(256), 0, stream>>>(bufB, w5, b5, bufA, 64, 1);
    conv3x3<64><<<dim3(256, 96, 2), dim3(256), 0, stream>>>(bufA, w6, b6, bufB, 96, 0);

    // 3) pool to 16x16 grid
    pool16<<<dim3((2 * 96 * 256 + 255) / 256), dim3(256), 0, stream>>>(bufB, c16);

    // 4) fused guide + slice + apply
    slice_apply<<<dim3((2 * HW1K + 255) / 256), dim3(256), 0, stream>>>(x, c16, out);

    (void)in_sizes; (void)n_in; (void)out_size; (void)ws_size;
}

// Round 2
// 904.798 us; speedup vs baseline: 3.8140x; 3.8140x over previous
//
#include <hip/hip_runtime.h>
#include <hip/hip_bf16.h>

#define HW256 65536      // 256*256
#define HW1K  1048576    // 1024*1024

// ---------------------------------------------------------------------------
// 4x bilinear downsample 1024->256. scale=4 => exact 2x2 average of rows
// 4i+1,4i+2 / cols 4j+1,4j+2.
__global__ void downsample4(const float* __restrict__ x, float* __restrict__ out) {
    int idx = blockIdx.x * blockDim.x + threadIdx.x;
    if (idx >= 2 * 3 * HW256) return;
    int xo = idx & 255;
    int yo = (idx >> 8) & 255;
    int c  = idx >> 16;                // b*3+ch, 0..5
    const float* p = x + (size_t)c * HW1K;
    int yi = 4 * yo + 1, xi = 4 * xo + 1;
    float s = p[yi * 1024 + xi] + p[yi * 1024 + xi + 1]
            + p[(yi + 1) * 1024 + xi] + p[(yi + 1) * 1024 + xi + 1];
    out[idx] = 0.25f * s;
}

// ---------------------------------------------------------------------------
// Register-tiled direct 3x3 SAME conv, NCHW, 256x256.
// One block = one output row (256 threads = 256 px), NCO output channels per
// thread held in registers. Input window (9 vals) loaded once per ci and
// reused for all NCO outputs -> 9*NCO FMAs per 9 (L1-hit) loads.
// Weight addresses are wave-uniform -> scalar loads (SGPR operand in FMA).
template <int CIN, int NCO>
__global__ __launch_bounds__(256)
void conv3x3_rt(const float* __restrict__ in, const float* __restrict__ wgt,
                const float* __restrict__ bias, float* __restrict__ out,
                int cout, int do_relu) {
    const int x   = threadIdx.x;       // 0..255
    const int y   = blockIdx.x;        // 0..255
    const int co0 = blockIdx.y * NCO;
    const int b   = blockIdx.z;

    float acc[NCO];
    #pragma unroll
    for (int c = 0; c < NCO; ++c) acc[c] = bias[co0 + c];

    const float* inb = in + (size_t)b * CIN * HW256;

    for (int ci = 0; ci < CIN; ++ci) {
        const float* inc = inb + (size_t)ci * HW256;
        float v[9];
        #pragma unroll
        for (int ky = 0; ky < 3; ++ky) {
            int yy = y + ky - 1;
            bool yok = (yy >= 0) && (yy <= 255);
            const float* row = inc + yy * 256;
            v[ky * 3 + 0] = (yok && x >= 1)   ? row[x - 1] : 0.0f;
            v[ky * 3 + 1] = yok               ? row[x]     : 0.0f;
            v[ky * 3 + 2] = (yok && x <= 254) ? row[x + 1] : 0.0f;
        }
        const float* wci = wgt + (size_t)co0 * CIN * 9 + ci * 9;
        #pragma unroll
        for (int c = 0; c < NCO; ++c) {
            const float* wk = wci + (size_t)c * CIN * 9;
            float a = acc[c];
            a = fmaf(wk[0], v[0], a); a = fmaf(wk[1], v[1], a); a = fmaf(wk[2], v[2], a);
            a = fmaf(wk[3], v[3], a); a = fmaf(wk[4], v[4], a); a = fmaf(wk[5], v[5], a);
            a = fmaf(wk[6], v[6], a); a = fmaf(wk[7], v[7], a); a = fmaf(wk[8], v[8], a);
            acc[c] = a;
        }
    }

    float* ob = out + (size_t)(b * cout + co0) * HW256 + y * 256 + x;
    #pragma unroll
    for (int c = 0; c < NCO; ++c) {
        float a = acc[c];
        if (do_relu) a = fmaxf(a, 0.0f);
        ob[(size_t)c * HW256] = a;
    }
}

// ---------------------------------------------------------------------------
// 16x bilinear downsample 256->16 (96 ch): exact 2x2 average of rows 16i+7,8.
__global__ void pool16(const float* __restrict__ in, float* __restrict__ out) {
    int idx = blockIdx.x * blockDim.x + threadIdx.x;
    if (idx >= 2 * 96 * 256) return;
    int gx = idx & 15;
    int gy = (idx >> 4) & 15;
    int c  = idx >> 8;                 // b*96+ch
    const float* p = in + (size_t)c * HW256;
    int yi = 16 * gy + 7, xi = 16 * gx + 7;
    float s = p[yi * 256 + xi] + p[yi * 256 + xi + 1]
            + p[(yi + 1) * 256 + xi] + p[(yi + 1) * 256 + xi + 1];
    out[idx] = 0.25f * s;
}

// ---------------------------------------------------------------------------
// Fused guide + trilinear grid slice + affine + clip.
// c16 layout: (B, 96, 16, 16); grid[b,p,gy,gx,d] == c16[b, p*8+d, gy, gx].
__global__ void slice_apply(const float* __restrict__ x, const float* __restrict__ c16,
                            float* __restrict__ out) {
    int idx = blockIdx.x * blockDim.x + threadIdx.x;
    if (idx >= 2 * HW1K) return;
    int px = idx & 1023;
    int py = (idx >> 10) & 1023;
    int b  = idx >> 20;

    const float* xb = x + (size_t)b * 3 * HW1K;
    int po = py * 1024 + px;
    float r  = xb[po];
    float g  = xb[HW1K + po];
    float bl = xb[2 * HW1K + po];

    float gd = fminf(fmaxf(0.299f * r + 0.587f * g + 0.114f * bl, 0.0f), 1.0f);

    float ysf = (float)py * (15.0f / 1023.0f);
    float xsf = (float)px * (15.0f / 1023.0f);
    int y0 = (int)floorf(ysf); int y1 = min(y0 + 1, 15);
    int x0 = (int)floorf(xsf); int x1 = min(x0 + 1, 15);
    float wy = ysf - (float)y0;
    float wx = xsf - (float)x0;

    float d  = gd * 7.0f;
    int d0 = (int)floorf(d); d0 = max(0, min(d0, 7));
    int d1 = min(d0 + 1, 7);
    float wd = fminf(fmaxf(d - (float)d0, 0.0f), 1.0f);

    float w00 = (1.0f - wy) * (1.0f - wx);
    float w01 = (1.0f - wy) * wx;
    float w10 = wy * (1.0f - wx);
    float w11 = wy * wx;

    const float* gb = c16 + (size_t)b * 96 * 256;
    float co[12];
    #pragma unroll
    for (int p = 0; p < 12; ++p) {
        const float* gp = gb + p * 8 * 256;
        float v00 = (1.0f - wd) * gp[d0 * 256 + y0 * 16 + x0] + wd * gp[d1 * 256 + y0 * 16 + x0];
        float v01 = (1.0f - wd) * gp[d0 * 256 + y0 * 16 + x1] + wd * gp[d1 * 256 + y0 * 16 + x1];
        float v10 = (1.0f - wd) * gp[d0 * 256 + y1 * 16 + x0] + wd * gp[d1 * 256 + y1 * 16 + x0];
        float v11 = (1.0f - wd) * gp[d0 * 256 + y1 * 16 + x1] + wd * gp[d1 * 256 + y1 * 16 + x1];
        co[p] = w00 * v00 + w01 * v01 + w10 * v10 + w11 * v11;
    }

    float* ob = out + (size_t)b * 3 * HW1K;
    #pragma unroll
    for (int i = 0; i < 3; ++i) {
        float v = co[i * 4 + 0] * r + co[i * 4 + 1] * g + co[i * 4 + 2] * bl + co[i * 4 + 3];
        ob[i * HW1K + po] = fminf(fmaxf(v, 0.0f), 1.0f);
    }
}

// ---------------------------------------------------------------------------
extern "C" void kernel_launch(void* const* d_in, const int* in_sizes, int n_in,
                              void* d_out, int out_size, void* d_ws, size_t ws_size,
                              hipStream_t stream) {
    const float* x  = (const float*)d_in[0];
    const float* w1 = (const float*)d_in[1];  const float* b1 = (const float*)d_in[2];
    const float* w2 = (const float*)d_in[3];  const float* b2 = (const float*)d_in[4];
    const float* w3 = (const float*)d_in[5];  const float* b3 = (const float*)d_in[6];
    const float* w4 = (const float*)d_in[7];  const float* b4 = (const float*)d_in[8];
    const float* w5 = (const float*)d_in[9];  const float* b5 = (const float*)d_in[10];
    const float* w6 = (const float*)d_in[11]; const float* b6 = (const float*)d_in[12];
    float* out = (float*)d_out;

    float* bufA = (float*)d_ws;                 // 2*64*65536
    float* bufB = bufA + 8388608;               // 2*96*65536
    float* xlow = bufB + 12582912;              // 2*3*65536
    float* c16  = xlow + 393216;                // 2*96*256

    downsample4<<<dim3((2 * 3 * HW256 + 255) / 256), dim3(256), 0, stream>>>(x, xlow);

    // conv stack: grid = (row, cout/NCO, batch)
    conv3x3_rt<3, 16> <<<dim3(256, 1, 2), dim3(256), 0, stream>>>(xlow, w1, b1, bufA, 16, 1);
    conv3x3_rt<16, 32><<<dim3(256, 1, 2), dim3(256), 0, stream>>>(bufA, w2, b2, bufB, 32, 1);
    conv3x3_rt<32, 32><<<dim3(256, 1, 2), dim3(256), 0, stream>>>(bufB, w3, b3, bufA, 32, 1);
    conv3x3_rt<32, 32><<<dim3(256, 2, 2), dim3(256), 0, stream>>>(bufA, w4, b4, bufB, 64, 1);
    conv3x3_rt<64, 32><<<dim3(256, 2, 2), dim3(256), 0, stream>>>(bufB, w5, b5, bufA, 64, 1);
    conv3x3_rt<64, 32><<<dim3(256, 3, 2), dim3(256), 0, stream>>>(bufA, w6, b6, bufB, 96, 0);

    pool16<<<dim3((2 * 96 * 256 + 255) / 256), dim3(256), 0, stream>>>(bufB, c16);

    slice_apply<<<dim3((2 * HW1K + 255) / 256), dim3(256), 0, stream>>>(x, c16, out);

    (void)in_sizes; (void)n_in; (void)out_size; (void)ws_size;
}

// Round 3
// 164.533 us; speedup vs baseline: 20.9740x; 5.4992x over previous
//
#include <hip/hip_runtime.h>
#include <hip/hip_bf16.h>

#define HW1K  1048576    // 1024*1024

// Weight-prep: transpose OIHW -> wp[layer_base + (ci*9+ky*3+kx)*COUT + co]
// so the fused kernel's weight loads are coalesced over co.
// Layer bases (floats): L1@0(432) L2@432(4608) L3@5040(9216) L4@14256(18432)
// L5@32688(36864) L6@69552(55296), total 124848.
__global__ void prep_w(const float* __restrict__ w1, const float* __restrict__ w2,
                       const float* __restrict__ w3, const float* __restrict__ w4,
                       const float* __restrict__ w5, const float* __restrict__ w6,
                       float* __restrict__ wp) {
    int i = blockIdx.x * 256 + threadIdx.x;
    if (i >= 124848) return;
    const float* src; int base, cin, cout;
    if      (i < 432)   { src = w1; base = 0;     cin = 3;  cout = 16; }
    else if (i < 5040)  { src = w2; base = 432;   cin = 16; cout = 32; }
    else if (i < 14256) { src = w3; base = 5040;  cin = 32; cout = 32; }
    else if (i < 32688) { src = w4; base = 14256; cin = 32; cout = 64; }
    else if (i < 69552) { src = w5; base = 32688; cin = 64; cout = 64; }
    else                { src = w6; base = 69552; cin = 64; cout = 96; }
    int r  = i - base;
    int kk = r / cout;
    int co = r % cout;
    int ci = kk / 9;
    int t9 = kk % 9;
    wp[i] = src[(co * cin + ci) * 9 + t9];
}

// ---------------------------------------------------------------------------
// One VALID 3x3 conv layer on LDS tiles. In: [WIN][WIN][CIN], out
// [WOUT][WOUT][COUT], WOUT=WIN-2. Thread = (co = tid%COUT, px-group =
// tid/COUT covering PXG pixels). Weight loads coalesced over co; activation
// LDS reads wave-uniform (broadcast) within each co-group.
template <int WIN, int CIN, int COUT, int PXG, int RELU>
__device__ __forceinline__ void layer(const float* __restrict__ sIn, float* __restrict__ sOut,
                                      const float* __restrict__ wp, const float* __restrict__ bias) {
    constexpr int WOUT = WIN - 2;
    constexpr int NPX  = WOUT * WOUT;
    const int tid = threadIdx.x;
    const int co  = tid % COUT;
    const int p0  = (tid / COUT) * PXG;

    float acc[PXG];
    const float bs = bias[co];
    #pragma unroll
    for (int pp = 0; pp < PXG; ++pp) acc[pp] = bs;

    int basec[PXG];
    #pragma unroll
    for (int pp = 0; pp < PXG; ++pp) {
        int px = p0 + pp; if (px >= NPX) px = NPX - 1;   // keep addr valid
        basec[pp] = ((px / WOUT) * WIN + (px % WOUT)) * CIN;
    }

    for (int ci = 0; ci < CIN; ++ci) {
        #pragma unroll
        for (int ky = 0; ky < 3; ++ky) {
            #pragma unroll
            for (int kx = 0; kx < 3; ++kx) {
                float w  = wp[(ci * 9 + ky * 3 + kx) * COUT + co];
                int  off = (ky * WIN + kx) * CIN + ci;
                #pragma unroll
                for (int pp = 0; pp < PXG; ++pp)
                    acc[pp] = fmaf(w, sIn[basec[pp] + off], acc[pp]);
            }
        }
    }

    #pragma unroll
    for (int pp = 0; pp < PXG; ++pp) {
        int px = p0 + pp;
        if (px < NPX) {
            float a = acc[pp];
            if (RELU) a = fmaxf(a, 0.0f);
            sOut[px * COUT + co] = a;
        }
    }
}

// ---------------------------------------------------------------------------
// Fully fused per-grid-cell pipeline: block = (gx, gy, b). Computes the
// dependency cone of one 16x16 grid cell: 14x14x3 downsampled input ->
// conv1..conv6 (VALID, shrinking 14->12->10->8->6->4->2) -> 2x2 avg pool ->
// c16[b][gy][gx][d][p] (p-contiguous for vectorized slice loads).
// Cone coords stay in [1,254]: zero-padding never triggers.
__global__ __launch_bounds__(256)
void fused_cone(const float* __restrict__ x, const float* __restrict__ wp,
                const float* __restrict__ b1, const float* __restrict__ b2,
                const float* __restrict__ b3, const float* __restrict__ b4,
                const float* __restrict__ b5, const float* __restrict__ b6,
                float* __restrict__ c16) {
    __shared__ float sA[3200];   // xin(588) / t2(3200) / t4(2304) / t6(384)
    __shared__ float sB[2304];   // t1(2304) / t3(2048) / t5(1024)

    const int gx = blockIdx.x, gy = blockIdx.y, b = blockIdx.z;
    const float* xb = x + (size_t)b * 3 * HW1K;

    // xin: xlow cone [14][14][3]; xlow[y][x] = avg of x rows 4y+1..4y+2,
    // cols 4x+1..4x+2 (exact bilinear 4x downsample).
    for (int i = threadIdx.x; i < 588; i += 256) {
        int c  = i % 3;
        int t  = i / 3;
        int xi = t % 14;
        int yi = t / 14;
        int ya = 16 * gy + 1 + yi;
        int xa = 16 * gx + 1 + xi;
        const float* p = xb + (size_t)c * HW1K + (4 * ya + 1) * 1024 + (4 * xa + 1);
        sA[(yi * 14 + xi) * 3 + c] = 0.25f * (p[0] + p[1] + p[1024] + p[1025]);
    }
    __syncthreads();

    layer<14, 3, 16, 9, 1>(sA, sB, wp + 0,     b1); __syncthreads();  // 12x12x16
    layer<12, 16, 32, 13, 1>(sB, sA, wp + 432,   b2); __syncthreads();  // 10x10x32
    layer<10, 32, 32, 8, 1>(sA, sB, wp + 5040,  b3); __syncthreads();  // 8x8x32
    layer<8, 32, 64, 9, 1>(sB, sA, wp + 14256, b4); __syncthreads();  // 6x6x64
    layer<6, 64, 64, 4, 1>(sA, sB, wp + 32688, b5); __syncthreads();  // 4x4x64
    layer<4, 64, 96, 2, 0>(sB, sA, wp + 69552, b6); __syncthreads();  // 2x2x96

    // pool 2x2 (exact 16x bilinear downsample) + write c16[b][gy][gx][d][p]
    for (int ch = threadIdx.x; ch < 96; ch += 256) {
        float v = 0.25f * (sA[ch] + sA[96 + ch] + sA[192 + ch] + sA[288 + ch]);
        int p = ch >> 3, d = ch & 7;
        c16[(size_t)b * 24576 + ((gy * 16 + gx) * 8 + d) * 12 + p] = v;
    }
}

// ---------------------------------------------------------------------------
// Fused guide + trilinear slice + affine + clip.
// c16 layout: [b][gy*16+gx][d][p=12], p contiguous -> dwordx4 loads.
__global__ void slice_apply(const float* __restrict__ x, const float* __restrict__ c16,
                            float* __restrict__ out) {
    int idx = blockIdx.x * blockDim.x + threadIdx.x;
    if (idx >= 2 * HW1K) return;
    int px = idx & 1023;
    int py = (idx >> 10) & 1023;
    int b  = idx >> 20;

    const float* xb = x + (size_t)b * 3 * HW1K;
    int po = py * 1024 + px;
    float r  = xb[po];
    float g  = xb[HW1K + po];
    float bl = xb[2 * HW1K + po];

    float gd = fminf(fmaxf(0.299f * r + 0.587f * g + 0.114f * bl, 0.0f), 1.0f);

    float ysf = (float)py * (15.0f / 1023.0f);
    float xsf = (float)px * (15.0f / 1023.0f);
    int y0 = (int)floorf(ysf); int y1 = min(y0 + 1, 15);
    int x0 = (int)floorf(xsf); int x1 = min(x0 + 1, 15);
    float wy = ysf - (float)y0;
    float wx = xsf - (float)x0;

    float d  = gd * 7.0f;
    int d0 = (int)floorf(d); d0 = max(0, min(d0, 7));
    int d1 = min(d0 + 1, 7);
    float wd = fminf(fmaxf(d - (float)d0, 0.0f), 1.0f);

    const float* gb = c16 + (size_t)b * 24576;
    float co[12];
    #pragma unroll
    for (int p = 0; p < 12; ++p) co[p] = 0.0f;

    #pragma unroll
    for (int cy = 0; cy < 2; ++cy) {
        int   yy  = cy ? y1 : y0;
        float wyf = cy ? wy : 1.0f - wy;
        #pragma unroll
        for (int cx = 0; cx < 2; ++cx) {
            int   xx  = cx ? x1 : x0;
            float wyx = wyf * (cx ? wx : 1.0f - wx);
            const float* g0 = gb + ((yy * 16 + xx) * 8 + d0) * 12;
            const float* g1 = gb + ((yy * 16 + xx) * 8 + d1) * 12;
            float wA = wyx * (1.0f - wd), wB = wyx * wd;
            #pragma unroll
            for (int p = 0; p < 12; ++p) co[p] += wA * g0[p] + wB * g1[p];
        }
    }

    float* ob = out + (size_t)b * 3 * HW1K;
    #pragma unroll
    for (int i = 0; i < 3; ++i) {
        float v = co[i * 4 + 0] * r + co[i * 4 + 1] * g + co[i * 4 + 2] * bl + co[i * 4 + 3];
        ob[i * HW1K + po] = fminf(fmaxf(v, 0.0f), 1.0f);
    }
}

// ---------------------------------------------------------------------------
extern "C" void kernel_launch(void* const* d_in, const int* in_sizes, int n_in,
                              void* d_out, int out_size, void* d_ws, size_t ws_size,
                              hipStream_t stream) {
    const float* x  = (const float*)d_in[0];
    const float* w1 = (const float*)d_in[1];  const float* b1 = (const float*)d_in[2];
    const float* w2 = (const float*)d_in[3];  const float* b2 = (const float*)d_in[4];
    const float* w3 = (const float*)d_in[5];  const float* b3 = (const float*)d_in[6];
    const float* w4 = (const float*)d_in[7];  const float* b4 = (const float*)d_in[8];
    const float* w5 = (const float*)d_in[9];  const float* b5 = (const float*)d_in[10];
    const float* w6 = (const float*)d_in[11]; const float* b6 = (const float*)d_in[12];
    float* out = (float*)d_out;

    float* wp  = (float*)d_ws;      // 124848 floats
    float* c16 = wp + 124848;       // 2*24576 floats

    prep_w<<<dim3((124848 + 255) / 256), dim3(256), 0, stream>>>(w1, w2, w3, w4, w5, w6, wp);
    fused_cone<<<dim3(16, 16, 2), dim3(256), 0, stream>>>(x, wp, b1, b2, b3, b4, b5, b6, c16);
    slice_apply<<<dim3((2 * HW1K + 255) / 256), dim3(256), 0, stream>>>(x, c16, out);

    (void)in_sizes; (void)n_in; (void)out_size; (void)ws_size;
}